// Round 3
// baseline (1572.966 us; speedup 1.0000x reference)
//
#include <hip/hip_runtime.h>
#include <hip/hip_fp16.h>
#include <stdint.h>

// Int8Linear: y[m,n] = fp16round((sum_k x[m,k] * (fp16)W[n,k]) * scale[n]).
// Harness wire dtypes (canonicalized): x -> float32, weight_int8 -> int32,
// scale -> float32, OUTPUT -> float32 (fp16 values upcast).
// M=8192 (B*S), K=4096, N=11008.
// Plan: pre-pass converts W (int32->fp16) and X (fp32->fp16) into d_ws, then
// m97-structure 128x128 MFMA GEMM (B^T layout), fp32 accum, scale epilogue.

typedef _Float16 half8 __attribute__((ext_vector_type(8)));
typedef float floatx4 __attribute__((ext_vector_type(4)));

constexpr int Mdim = 8192;
constexpr int Ndim = 11008;
constexpr int Kdim = 4096;
constexpr int BM = 128, BN = 128, BK = 64;
constexpr int NT = Kdim / BK;
constexpr int GX = Ndim / BN;           // 86
constexpr int GY = Mdim / BM;           // 64
constexpr int NWG = GX * GY;            // 5504, % 8 == 0 -> simple swizzle bijective
constexpr int PER_XCD = NWG / 8;        // 688

// global -> LDS direct (16B/lane). LDS dest must be wave-uniform base; HW adds lane*16.
#define GLD16(gp, lp) __builtin_amdgcn_global_load_lds(                        \
    (const __attribute__((address_space(1))) void*)(gp),                       \
    (__attribute__((address_space(3))) void*)(lp), 16, 0, 0)

__device__ inline half8 cvt_i8(int4 a, int4 b) {
  half8 h;
  h[0] = (_Float16)a.x; h[1] = (_Float16)a.y; h[2] = (_Float16)a.z; h[3] = (_Float16)a.w;
  h[4] = (_Float16)b.x; h[5] = (_Float16)b.y; h[6] = (_Float16)b.z; h[7] = (_Float16)b.w;
  return h;
}
__device__ inline half8 cvt_f8(float4 a, float4 b) {
  half8 h;
  h[0] = (_Float16)a.x; h[1] = (_Float16)a.y; h[2] = (_Float16)a.z; h[3] = (_Float16)a.w;
  h[4] = (_Float16)b.x; h[5] = (_Float16)b.y; h[6] = (_Float16)b.z; h[7] = (_Float16)b.w;
  return h;
}

// -------- pre-pass: W int32 [N*K] -> fp16 --------
__global__ __launch_bounds__(256) void conv_w(const int* __restrict__ w,
                                              _Float16* __restrict__ o) {
  const long n8 = (long)Ndim * Kdim / 8;
  const long stride = (long)gridDim.x * blockDim.x;
  const int4* __restrict__ src = (const int4*)w;
  half8* __restrict__ dst = (half8*)o;
  for (long i = (long)blockIdx.x * blockDim.x + threadIdx.x; i < n8; i += stride)
    dst[i] = cvt_i8(src[2 * i], src[2 * i + 1]);
}

// -------- pre-pass: X fp32 [M*K] -> fp16 --------
__global__ __launch_bounds__(256) void conv_x(const float* __restrict__ x,
                                              _Float16* __restrict__ o) {
  const long n8 = (long)Mdim * Kdim / 8;
  const long stride = (long)gridDim.x * blockDim.x;
  const float4* __restrict__ src = (const float4*)x;
  half8* __restrict__ dst = (half8*)o;
  for (long i = (long)blockIdx.x * blockDim.x + threadIdx.x; i < n8; i += stride)
    dst[i] = cvt_f8(src[2 * i], src[2 * i + 1]);
}

// -------- GEMM: C[M,N] = A[M,K] * W[N,K]^T, fp32 acc, scale[n] epilogue ------
// 256 threads = 4 waves (2x2), each wave owns a 64x64 sub-tile (4x4 frags of
// 16x16). mfma_f32_16x16x32_f16: A row = lane&15, k = (lane>>4)*8+j;
// B col = lane&15 (= W row n), same k; D: row=(lane>>4)*4+reg, col=lane&15.
// CONVA: stage A in-kernel from fp32 global. CONVB: stage B in-kernel from int32.
template <bool CONVA, bool CONVB>
__global__ __launch_bounds__(256) void int8lin_gemm(
    const _Float16* __restrict__ Xh, const float* __restrict__ Xf,
    const _Float16* __restrict__ Wh, const int* __restrict__ W32,
    const float* __restrict__ scale, float* __restrict__ Y) {
  __shared__ _Float16 As[BM * BK];  // [row m][k] 128x64, 16 KB
  __shared__ _Float16 Bs[BN * BK];  // [row n][k] 128x64, 16 KB

  const int tid = threadIdx.x;
  const int lane = tid & 63;
  const int wave = tid >> 6;
  const int wr = wave >> 1, wc = wave & 1;

  // T1: bijective XCD swizzle (NWG % 8 == 0).
  const int bid = blockIdx.x;
  const int swz = (bid & 7) * PER_XCD + (bid >> 3);
  const int bn0 = (swz % GX) * BN;
  const int bm0 = (swz / GX) * BM;

  floatx4 acc[4][4] = {};

  for (int t = 0; t < NT; ++t) {
    const int kt = t * BK;
    // ---- stage A tile ----
    if constexpr (!CONVA) {
      const _Float16* Ag = Xh + (size_t)bm0 * Kdim;
#pragma unroll
      for (int r = 0; r < 4; ++r) {
        const int o = ((r * 4 + wave) << 10) | (lane << 4);  // byte off in tile
        const int row = o >> 7;          // 128 B per row (64 f16)
        const int col = (o & 127) >> 1;  // f16 elements
        GLD16(Ag + (size_t)row * Kdim + kt + col, As + ((r * 4 + wave) << 9));
      }
    } else {
      const int e0 = tid << 5;          // 32 elems/thread
      const int row = e0 >> 6, col = e0 & 63;
      const float* gp = Xf + (size_t)(bm0 + row) * Kdim + kt + col;
      half8* lp = (half8*)&As[row * BK + col];
#pragma unroll
      for (int v = 0; v < 4; ++v)
        lp[v] = cvt_f8(((const float4*)gp)[2 * v], ((const float4*)gp)[2 * v + 1]);
    }
    // ---- stage B tile ----
    if constexpr (!CONVB) {
      const _Float16* Bg = Wh + (size_t)bn0 * Kdim;
#pragma unroll
      for (int r = 0; r < 4; ++r) {
        const int o = ((r * 4 + wave) << 10) | (lane << 4);
        const int row = o >> 7;
        const int col = (o & 127) >> 1;
        GLD16(Bg + (size_t)row * Kdim + kt + col, Bs + ((r * 4 + wave) << 9));
      }
    } else {
      const int e0 = tid << 5;
      const int row = e0 >> 6, col = e0 & 63;
      const int* gp = W32 + (size_t)(bn0 + row) * Kdim + kt + col;
      half8* lp = (half8*)&Bs[row * BK + col];
#pragma unroll
      for (int v = 0; v < 4; ++v)
        lp[v] = cvt_i8(((const int4*)gp)[2 * v], ((const int4*)gp)[2 * v + 1]);
    }
    __syncthreads();  // compiler drains vmcnt/lgkmcnt before s_barrier

    // ---- compute: BK=64 as 2 k-slices of 32 ----
#pragma unroll
    for (int ks = 0; ks < 2; ++ks) {
      half8 af[4], bf[4];
#pragma unroll
      for (int i = 0; i < 4; ++i)
        af[i] = *(const half8*)&As[(wr * 64 + i * 16 + (lane & 15)) * BK +
                                   ks * 32 + (lane >> 4) * 8];
#pragma unroll
      for (int i = 0; i < 4; ++i)
        bf[i] = *(const half8*)&Bs[(wc * 64 + i * 16 + (lane & 15)) * BK +
                                   ks * 32 + (lane >> 4) * 8];
#pragma unroll
      for (int m = 0; m < 4; ++m)
#pragma unroll
        for (int n = 0; n < 4; ++n)
          acc[m][n] =
              __builtin_amdgcn_mfma_f32_16x16x32_f16(af[m], bf[n], acc[m][n], 0, 0, 0);
    }
    __syncthreads();
  }

  // ---- epilogue: fp16round(acc * scale[n]) stored as fp32 ----
  float sc[4];
#pragma unroll
  for (int n = 0; n < 4; ++n)
    sc[n] = scale[bn0 + wc * 64 + n * 16 + (lane & 15)];
#pragma unroll
  for (int m = 0; m < 4; ++m) {
    const int row0 = bm0 + wr * 64 + m * 16 + (lane >> 4) * 4;
#pragma unroll
    for (int n = 0; n < 4; ++n) {
      const int col = bn0 + wc * 64 + n * 16 + (lane & 15);
#pragma unroll
      for (int i = 0; i < 4; ++i)
        Y[(size_t)(row0 + i) * Ndim + col] =
            (float)(_Float16)(acc[m][n][i] * sc[n]);
    }
  }
}

extern "C" void kernel_launch(void* const* d_in, const int* in_sizes, int n_in,
                              void* d_out, int out_size, void* d_ws, size_t ws_size,
                              hipStream_t stream) {
  const float* X = (const float*)d_in[0];
  const int* W32 = (const int*)d_in[1];
  const float* scale = (const float*)d_in[2];
  float* Y = (float*)d_out;

  const size_t wbytes = (size_t)Ndim * Kdim * sizeof(_Float16);  // 86 MiB
  const size_t xbytes = (size_t)Mdim * Kdim * sizeof(_Float16);  // 64 MiB

  if (ws_size >= wbytes + xbytes) {
    _Float16* Wh = (_Float16*)d_ws;
    _Float16* Xh = (_Float16*)((char*)d_ws + wbytes);
    conv_w<<<2048, 256, 0, stream>>>(W32, Wh);
    conv_x<<<2048, 256, 0, stream>>>(X, Xh);
    int8lin_gemm<false, false><<<NWG, 256, 0, stream>>>(Xh, nullptr, Wh, nullptr, scale, Y);
  } else if (ws_size >= wbytes) {
    _Float16* Wh = (_Float16*)d_ws;
    conv_w<<<2048, 256, 0, stream>>>(W32, Wh);
    int8lin_gemm<true, false><<<NWG, 256, 0, stream>>>(nullptr, X, Wh, nullptr, scale, Y);
  } else {
    int8lin_gemm<true, true><<<NWG, 256, 0, stream>>>(nullptr, X, nullptr, W32, scale, Y);
  }
}

// Round 4
// 1225.655 us; speedup vs baseline: 1.2834x; 1.2834x over previous
//
#include <hip/hip_runtime.h>
#include <hip/hip_fp16.h>
#include <stdint.h>

// Int8Linear: y[m,n] = fp16round((sum_k x[m,k] * (fp16)W[n,k]) * scale[n]).
// Wire dtypes: x fp32, weight int32, scale fp32, out fp32 (fp16 values).
// M=8192, K=4096, N=11008.
// This round: 256x256 8-phase template (T1 XCD swizzle + T2 st_16x32 LDS
// swizzle + T3/T4 counted-vmcnt 8-phase pipeline + T5 setprio), f16 MFMA.

typedef _Float16 half8 __attribute__((ext_vector_type(8)));
typedef float floatx4 __attribute__((ext_vector_type(4)));

constexpr int Mdim = 8192;
constexpr int Ndim = 11008;
constexpr int Kdim = 4096;
constexpr int BM = 256, BN = 256, BK = 64;
constexpr int NT = Kdim / BK;   // 64
constexpr int GX = Ndim / BN;   // 43
constexpr int GY = Mdim / BM;   // 32
constexpr int NWG = GX * GY;    // 1376 (%8==0 -> simple XCD swizzle bijective)
constexpr int PER_XCD = NWG / 8;

#define GLD16(gp, lp) __builtin_amdgcn_global_load_lds(                        \
    (const __attribute__((address_space(1))) void*)(gp),                       \
    (__attribute__((address_space(3))) void*)(lp), 16, 0, 0)

__device__ inline half8 cvt_i8(int4 a, int4 b) {
  half8 h;
  h[0] = (_Float16)a.x; h[1] = (_Float16)a.y; h[2] = (_Float16)a.z; h[3] = (_Float16)a.w;
  h[4] = (_Float16)b.x; h[5] = (_Float16)b.y; h[6] = (_Float16)b.z; h[7] = (_Float16)b.w;
  return h;
}
__device__ inline half8 cvt_f8(float4 a, float4 b) {
  half8 h;
  h[0] = (_Float16)a.x; h[1] = (_Float16)a.y; h[2] = (_Float16)a.z; h[3] = (_Float16)a.w;
  h[4] = (_Float16)b.x; h[5] = (_Float16)b.y; h[6] = (_Float16)b.z; h[7] = (_Float16)b.w;
  return h;
}

// -------- merged pre-pass: W int32->fp16 and X fp32->fp16, overlapped -------
constexpr int WBLK = 2304;  // ~56% of 4096 blocks for W (270MB of 471MB traffic)
__global__ __launch_bounds__(256) void conv_both(const int* __restrict__ w,
                                                 const float* __restrict__ x,
                                                 _Float16* __restrict__ wo,
                                                 _Float16* __restrict__ xo) {
  if (blockIdx.x < WBLK) {
    const long n8 = (long)Ndim * Kdim / 8;
    const long stride = (long)WBLK * blockDim.x;
    const int4* __restrict__ src = (const int4*)w;
    half8* __restrict__ dst = (half8*)wo;
    for (long i = (long)blockIdx.x * blockDim.x + threadIdx.x; i < n8; i += stride)
      dst[i] = cvt_i8(src[2 * i], src[2 * i + 1]);
  } else {
    const long n8 = (long)Mdim * Kdim / 8;
    const int nb = gridDim.x - WBLK;
    const long stride = (long)nb * blockDim.x;
    const float4* __restrict__ src = (const float4*)x;
    half8* __restrict__ dst = (half8*)xo;
    for (long i = (long)(blockIdx.x - WBLK) * blockDim.x + threadIdx.x; i < n8;
         i += stride)
      dst[i] = cvt_f8(src[2 * i], src[2 * i + 1]);
  }
}

// ---------------- 256x256 8-phase GEMM ----------------
// 512 threads = 8 waves (2M x 4N); per-wave C = 128x64 = acc[8][4] frags.
// LDS: 2 bufs x (A 32KB + B 32KB) = 128KB, layout [256][64] f16, st_16x32
// swizzled (byte ^= ((byte>>9)&1)<<5 == col ^= ((row>>2)&1)*16 f16 elems).
// Staging: linear LDS dest (global_load_lds), inverse-swizzled global source.
// Schedule per K-tile t (4 phases, quadrants of per-wave C x full BK):
//   P1: ds_read A(mh0) 8x + B(np0) 4x | stage A-h0(t+1)->buf^1 | mfma q0
//   P2: ds_read B(np1) 4x             | stage A-h1(t+1)->buf^1 | mfma q1
//   P3: ds_read A(mh1) 8x             | stage B-h0(t+2)->buf   | mfma q2
//   P4: (no reads)                    | stage B-h1(t+2)->buf   | mfma q3
//       vmcnt(4) [leaves B(t+2) in flight], barrier.
// Race-safety: B region of buf last read in P2 (lgkmcnt(0)+barrier) before
// P3/P4 stages overwrite it; A region of buf^1 last read by tile t-1 (done).
__global__ __launch_bounds__(512, 2) void gemm8(
    const _Float16* __restrict__ Xh, const _Float16* __restrict__ Wh,
    const float* __restrict__ scale, float* __restrict__ Y) {
  __shared__ _Float16 lds[2][2][BM * BK];  // [buf][A=0/B=1][256*64] = 128 KB

  const int tid = threadIdx.x;
  const int lane = tid & 63;
  const int wave = tid >> 6;   // 0..7
  const int wr = wave >> 2;    // 0..1 (M)
  const int wcn = wave & 3;    // 0..3 (N)

  const int bid = blockIdx.x;
  const int swz = (bid & 7) * PER_XCD + (bid >> 3);
  const int bn0 = (swz % GX) * BN;
  const int bm0 = (swz / GX) * BM;

  const _Float16* Ag = Xh + (size_t)bm0 * Kdim;
  const _Float16* Bg = Wh + (size_t)bn0 * Kdim;

  // staging source coords (pre-swizzle: lanes 32-63 flip col by 16 f16)
  const int srow = (wave << 3) + (lane >> 3);                    // +h*128+r*64
  const int scol = ((lane & 7) * 8) ^ (((lane >> 5) & 1) << 4);  // f16 elems

  auto stage = [&](int buf, int op, int h, int t) {
    const _Float16* G = op ? Bg : Ag;
    const int kt = t * BK;
#pragma unroll
    for (int r = 0; r < 2; ++r) {
      const _Float16* src = G + (size_t)(h * 128 + r * 64 + srow) * Kdim + kt + scol;
      char* dst = (char*)&lds[buf][op][0] + h * 16384 + r * 8192 + (wave << 10);
      GLD16(src, dst);  // HW adds lane*16 to wave-uniform dst
    }
  };
  auto ldsRd = [&](int buf, int op, int row, int cb) -> half8 {
    int b = row * 128 + cb;
    b ^= ((b >> 9) & 1) << 5;  // st_16x32 swizzle
    return *(const half8*)((const char*)&lds[buf][op][0] + b);
  };

  floatx4 acc[8][4] = {};

  // ---- prologue: tile0 all 4 halves, tile1 B halves; vmcnt(4); barrier ----
  stage(0, 0, 0, 0); stage(0, 0, 1, 0);
  stage(0, 1, 0, 0); stage(0, 1, 1, 0);
  stage(1, 1, 0, 1); stage(1, 1, 1, 1);
  asm volatile("s_waitcnt vmcnt(4)" ::: "memory");
  __builtin_amdgcn_s_barrier();

  for (int t = 0; t < NT; ++t) {
    const int cur = t & 1;
    const bool doA = (t + 1 < NT);
    const bool doB = (t + 2 < NT);
    half8 af[8], bf[2][4];
    const int cb0 = (lane >> 4) * 16;  // k-slice byte base per lane

    // ================ P1: quad (mh0, np0), 12 ds_reads ================
#pragma unroll
    for (int m2 = 0; m2 < 4; ++m2)
#pragma unroll
      for (int ks = 0; ks < 2; ++ks)
        af[m2 * 2 + ks] = ldsRd(cur, 0, wr * 128 + m2 * 16 + (lane & 15), ks * 64 + cb0);
#pragma unroll
    for (int n2 = 0; n2 < 2; ++n2)
#pragma unroll
      for (int ks = 0; ks < 2; ++ks)
        bf[0][n2 * 2 + ks] = ldsRd(cur, 1, wcn * 64 + n2 * 16 + (lane & 15), ks * 64 + cb0);
    if (doA) stage(cur ^ 1, 0, 0, t + 1);
    asm volatile("s_waitcnt lgkmcnt(8)" ::: "memory");
    __builtin_amdgcn_s_barrier();
    asm volatile("s_waitcnt lgkmcnt(0)" ::: "memory");
    __builtin_amdgcn_s_setprio(1);
#pragma unroll
    for (int m2 = 0; m2 < 4; ++m2)
#pragma unroll
      for (int n2 = 0; n2 < 2; ++n2)
#pragma unroll
        for (int ks = 0; ks < 2; ++ks)
          acc[m2][n2] = __builtin_amdgcn_mfma_f32_16x16x32_f16(
              af[m2 * 2 + ks], bf[0][n2 * 2 + ks], acc[m2][n2], 0, 0, 0);
    __builtin_amdgcn_s_setprio(0);
    __builtin_amdgcn_s_barrier();

    // ================ P2: quad (mh0, np1), 4 ds_reads ================
#pragma unroll
    for (int n2 = 0; n2 < 2; ++n2)
#pragma unroll
      for (int ks = 0; ks < 2; ++ks)
        bf[1][n2 * 2 + ks] =
            ldsRd(cur, 1, wcn * 64 + 32 + n2 * 16 + (lane & 15), ks * 64 + cb0);
    if (doA) stage(cur ^ 1, 0, 1, t + 1);
    __builtin_amdgcn_s_barrier();
    asm volatile("s_waitcnt lgkmcnt(0)" ::: "memory");
    __builtin_amdgcn_s_setprio(1);
#pragma unroll
    for (int m2 = 0; m2 < 4; ++m2)
#pragma unroll
      for (int n2 = 0; n2 < 2; ++n2)
#pragma unroll
        for (int ks = 0; ks < 2; ++ks)
          acc[m2][2 + n2] = __builtin_amdgcn_mfma_f32_16x16x32_f16(
              af[m2 * 2 + ks], bf[1][n2 * 2 + ks], acc[m2][2 + n2], 0, 0, 0);
    __builtin_amdgcn_s_setprio(0);
    __builtin_amdgcn_s_barrier();

    // ================ P3: quad (mh1, np0), 8 ds_reads ================
#pragma unroll
    for (int m2 = 0; m2 < 4; ++m2)
#pragma unroll
      for (int ks = 0; ks < 2; ++ks)
        af[m2 * 2 + ks] =
            ldsRd(cur, 0, wr * 128 + 64 + m2 * 16 + (lane & 15), ks * 64 + cb0);
    if (doB) stage(cur, 1, 0, t + 2);
    __builtin_amdgcn_s_barrier();
    asm volatile("s_waitcnt lgkmcnt(0)" ::: "memory");
    __builtin_amdgcn_s_setprio(1);
#pragma unroll
    for (int m2 = 0; m2 < 4; ++m2)
#pragma unroll
      for (int n2 = 0; n2 < 2; ++n2)
#pragma unroll
        for (int ks = 0; ks < 2; ++ks)
          acc[4 + m2][n2] = __builtin_amdgcn_mfma_f32_16x16x32_f16(
              af[m2 * 2 + ks], bf[0][n2 * 2 + ks], acc[4 + m2][n2], 0, 0, 0);
    __builtin_amdgcn_s_setprio(0);
    __builtin_amdgcn_s_barrier();

    // ================ P4: quad (mh1, np1), 0 ds_reads ================
    if (doB) stage(cur, 1, 1, t + 2);
    __builtin_amdgcn_s_barrier();
    __builtin_amdgcn_s_setprio(1);
#pragma unroll
    for (int m2 = 0; m2 < 4; ++m2)
#pragma unroll
      for (int n2 = 0; n2 < 2; ++n2)
#pragma unroll
        for (int ks = 0; ks < 2; ++ks)
          acc[4 + m2][2 + n2] = __builtin_amdgcn_mfma_f32_16x16x32_f16(
              af[m2 * 2 + ks], bf[1][n2 * 2 + ks], acc[4 + m2][2 + n2], 0, 0, 0);
    __builtin_amdgcn_s_setprio(0);
    if (doB) {
      asm volatile("s_waitcnt vmcnt(4)" ::: "memory");  // t+1 resident; B(t+2) in flight
    } else if (doA) {
      asm volatile("s_waitcnt vmcnt(0)" ::: "memory");  // tail: drain A(t+1)
    }
    __builtin_amdgcn_s_barrier();
  }

  // ---- epilogue: fp16round(acc * scale[n]) stored as fp32 ----
  float sc[4];
#pragma unroll
  for (int ni = 0; ni < 4; ++ni)
    sc[ni] = scale[bn0 + wcn * 64 + ni * 16 + (lane & 15)];
#pragma unroll
  for (int mi = 0; mi < 8; ++mi) {
    const int row0 = bm0 + wr * 128 + mi * 16 + (lane >> 4) * 4;
#pragma unroll
    for (int ni = 0; ni < 4; ++ni) {
      const int col = bn0 + wcn * 64 + ni * 16 + (lane & 15);
#pragma unroll
      for (int i = 0; i < 4; ++i)
        Y[(size_t)(row0 + i) * Ndim + col] = (float)(_Float16)(acc[mi][ni][i] * sc[ni]);
    }
  }
}

// ---------------- fallback (ws too small): fused-convert 128^2 ----------------
__global__ __launch_bounds__(256) void gemm_fused(
    const float* __restrict__ Xf, const int* __restrict__ W32,
    const float* __restrict__ scale, float* __restrict__ Y) {
  constexpr int bM = 128, bN = 128, bK = 64;
  __shared__ _Float16 As[bM * bK];
  __shared__ _Float16 Bs[bN * bK];
  const int tid = threadIdx.x, lane = tid & 63, wave = tid >> 6;
  const int wr2 = wave >> 1, wc2 = wave & 1;
  const int bn0 = (int)(blockIdx.x % (Ndim / bN)) * bN;
  const int bm0 = (int)(blockIdx.x / (Ndim / bN)) * bM;
  floatx4 acc[4][4] = {};
  for (int t = 0; t < Kdim / bK; ++t) {
    const int kt = t * bK;
    {
      const int e0 = tid << 5, row = e0 >> 6, col = e0 & 63;
      const float* gp = Xf + (size_t)(bm0 + row) * Kdim + kt + col;
      half8* lp = (half8*)&As[row * bK + col];
#pragma unroll
      for (int v = 0; v < 4; ++v)
        lp[v] = cvt_f8(((const float4*)gp)[2 * v], ((const float4*)gp)[2 * v + 1]);
      const int* gq = W32 + (size_t)(bn0 + row) * Kdim + kt + col;
      half8* lq = (half8*)&Bs[row * bK + col];
#pragma unroll
      for (int v = 0; v < 4; ++v)
        lq[v] = cvt_i8(((const int4*)gq)[2 * v], ((const int4*)gq)[2 * v + 1]);
    }
    __syncthreads();
#pragma unroll
    for (int ks = 0; ks < 2; ++ks) {
      half8 a4[4], b4[4];
#pragma unroll
      for (int i = 0; i < 4; ++i)
        a4[i] = *(const half8*)&As[(wr2 * 64 + i * 16 + (lane & 15)) * bK + ks * 32 + (lane >> 4) * 8];
#pragma unroll
      for (int i = 0; i < 4; ++i)
        b4[i] = *(const half8*)&Bs[(wc2 * 64 + i * 16 + (lane & 15)) * bK + ks * 32 + (lane >> 4) * 8];
#pragma unroll
      for (int m = 0; m < 4; ++m)
#pragma unroll
        for (int n = 0; n < 4; ++n)
          acc[m][n] = __builtin_amdgcn_mfma_f32_16x16x32_f16(a4[m], b4[n], acc[m][n], 0, 0, 0);
    }
    __syncthreads();
  }
  float sc[4];
#pragma unroll
  for (int n = 0; n < 4; ++n) sc[n] = scale[bn0 + wc2 * 64 + n * 16 + (lane & 15)];
#pragma unroll
  for (int m = 0; m < 4; ++m) {
    const int row0 = bm0 + wr2 * 64 + m * 16 + (lane >> 4) * 4;
#pragma unroll
    for (int n = 0; n < 4; ++n) {
      const int col = bn0 + wc2 * 64 + n * 16 + (lane & 15);
#pragma unroll
      for (int i = 0; i < 4; ++i)
        Y[(size_t)(row0 + i) * Ndim + col] = (float)(_Float16)(acc[m][n][i] * sc[n]);
    }
  }
}

extern "C" void kernel_launch(void* const* d_in, const int* in_sizes, int n_in,
                              void* d_out, int out_size, void* d_ws, size_t ws_size,
                              hipStream_t stream) {
  const float* X = (const float*)d_in[0];
  const int* W32 = (const int*)d_in[1];
  const float* scale = (const float*)d_in[2];
  float* Y = (float*)d_out;

  const size_t wbytes = (size_t)Ndim * Kdim * sizeof(_Float16);  // 86 MiB
  const size_t xbytes = (size_t)Mdim * Kdim * sizeof(_Float16);  // 64 MiB

  if (ws_size >= wbytes + xbytes) {
    _Float16* Wh = (_Float16*)d_ws;
    _Float16* Xh = (_Float16*)((char*)d_ws + wbytes);
    conv_both<<<4096, 256, 0, stream>>>(W32, X, Wh, Xh);
    gemm8<<<NWG, 512, 0, stream>>>(Xh, Wh, scale, Y);
  } else {
    gemm_fused<<<(Ndim / 128) * (Mdim / 128), 256, 0, stream>>>(X, W32, scale, Y);
  }
}

// Round 6
// 1158.527 us; speedup vs baseline: 1.3577x; 1.0579x over previous
//
#include <hip/hip_runtime.h>
#include <hip/hip_fp16.h>
#include <stdint.h>

// Int8Linear: y[m,n] = fp16round((sum_k x[m,k] * (fp16)W[n,k]) * scale[n]).
// Wire dtypes: x fp32, weight int32, scale fp32, out fp32 (fp16 values).
// M=8192, K=4096, N=11008.
// Round 6 (= round 5 resubmit, never ran): (a) 3-bit LDS XOR swizzle
// ((row&7)<<4) for conflict-free ds_read_b128 on 128B rows; (b)
// lane-contiguous conv pre-pass.

typedef _Float16 half8 __attribute__((ext_vector_type(8)));
typedef _Float16 half4 __attribute__((ext_vector_type(4)));
typedef float floatx4 __attribute__((ext_vector_type(4)));

constexpr int Mdim = 8192;
constexpr int Ndim = 11008;
constexpr int Kdim = 4096;
constexpr int BM = 256, BN = 256, BK = 64;
constexpr int NT = Kdim / BK;   // 64
constexpr int GX = Ndim / BN;   // 43
constexpr int GY = Mdim / BM;   // 32
constexpr int NWG = GX * GY;    // 1376 (%8==0 -> simple XCD swizzle bijective)
constexpr int PER_XCD = NWG / 8;

#define GLD16(gp, lp) __builtin_amdgcn_global_load_lds(                        \
    (const __attribute__((address_space(1))) void*)(gp),                       \
    (__attribute__((address_space(3))) void*)(lp), 16, 0, 0)

__device__ inline half4 cvt4i(int4 a) {
  half4 h;
  h[0] = (_Float16)a.x; h[1] = (_Float16)a.y; h[2] = (_Float16)a.z; h[3] = (_Float16)a.w;
  return h;
}
__device__ inline half4 cvt4f(float4 a) {
  half4 h;
  h[0] = (_Float16)a.x; h[1] = (_Float16)a.y; h[2] = (_Float16)a.z; h[3] = (_Float16)a.w;
  return h;
}
__device__ inline half8 cvt_i8(int4 a, int4 b) {
  half8 h;
  h[0] = (_Float16)a.x; h[1] = (_Float16)a.y; h[2] = (_Float16)a.z; h[3] = (_Float16)a.w;
  h[4] = (_Float16)b.x; h[5] = (_Float16)b.y; h[6] = (_Float16)b.z; h[7] = (_Float16)b.w;
  return h;
}
__device__ inline half8 cvt_f8(float4 a, float4 b) {
  half8 h;
  h[0] = (_Float16)a.x; h[1] = (_Float16)a.y; h[2] = (_Float16)a.z; h[3] = (_Float16)a.w;
  h[4] = (_Float16)b.x; h[5] = (_Float16)b.y; h[6] = (_Float16)b.z; h[7] = (_Float16)b.w;
  return h;
}

// -------- merged pre-pass, fully coalesced: thread i <-> 16B chunk i --------
constexpr int CONVB_TOT = 4096;
constexpr int WBLK = 2340;  // ~57% of blocks for W (270MB of 471MB traffic)
__global__ __launch_bounds__(256) void conv_both(const int* __restrict__ w,
                                                 const float* __restrict__ x,
                                                 _Float16* __restrict__ wo,
                                                 _Float16* __restrict__ xo) {
  if (blockIdx.x < WBLK) {
    const long n4 = (long)Ndim * Kdim / 4;       // int4 chunks
    const long stride = (long)WBLK * 256;
    const int4* __restrict__ src = (const int4*)w;
    half4* __restrict__ dst = (half4*)wo;
    for (long i = (long)blockIdx.x * 256 + threadIdx.x; i < n4; i += stride)
      dst[i] = cvt4i(src[i]);
  } else {
    const long n4 = (long)Mdim * Kdim / 4;       // float4 chunks
    const long stride = (long)(CONVB_TOT - WBLK) * 256;
    const float4* __restrict__ src = (const float4*)x;
    half4* __restrict__ dst = (half4*)xo;
    for (long i = (long)(blockIdx.x - WBLK) * 256 + threadIdx.x; i < n4; i += stride)
      dst[i] = cvt4f(src[i]);
  }
}

// ---------------- 256x256 8-phase GEMM ----------------
// 512 threads = 8 waves (2M x 4N); per-wave C = 128x64 = acc[8][4] frags.
// LDS: 2 bufs x (A 32KB + B 32KB) = 128KB, [256][64] f16 rows of 128B.
// Swizzle: byte ^= ((row&7)<<4) -- full 8-slot rotation per 8-row stripe.
//   A ds_read_b128 quad (16 rows x one slot) spreads over 8 distinct 4-bank
//   clusters, 2 lanes each (free); every consecutive-8-lane HW phase hits 8
//   distinct clusters -> conflict-free.
// Staging: linear LDS dest (global_load_lds adds lane*16 to uniform base);
//   lane l covers row l>>3, slot l&7 of its 1KB region -> inverse-swizzled
//   global source col = 8*((l&7)^(l>>3)) (within-row permutation, coalesced).
// Schedule per K-tile t (4 phases, quadrants of per-wave C x full BK):
//   P1: ds_read A(mh0) 8x + B(np0) 4x | stage A-h0(t+1)->buf^1 | mfma q0
//   P2: ds_read B(np1) 4x             | stage A-h1(t+1)->buf^1 | mfma q1
//   P3: ds_read A(mh1) 8x             | stage B-h0(t+2)->buf   | mfma q2
//   P4: (no reads)                    | stage B-h1(t+2)->buf   | mfma q3
//       vmcnt(4) [leaves B(t+2) in flight], barrier.
// Race-safety: B region of buf last read in P2 (lgkmcnt(0)+barrier) before
// P3/P4 stages overwrite it; A region of buf^1 last read by tile t-1 (done).
__global__ __launch_bounds__(512, 2) void gemm8(
    const _Float16* __restrict__ Xh, const _Float16* __restrict__ Wh,
    const float* __restrict__ scale, float* __restrict__ Y) {
  __shared__ _Float16 lds[2][2][BM * BK];  // [buf][A=0/B=1][256*64] = 128 KB

  const int tid = threadIdx.x;
  const int lane = tid & 63;
  const int wave = tid >> 6;   // 0..7
  const int wr = wave >> 2;    // 0..1 (M)
  const int wcn = wave & 3;    // 0..3 (N)

  const int bid = blockIdx.x;
  const int swz = (bid & 7) * PER_XCD + (bid >> 3);
  const int bn0 = (swz % GX) * BN;
  const int bm0 = (swz / GX) * BM;

  const _Float16* Ag = Xh + (size_t)bm0 * Kdim;
  const _Float16* Bg = Wh + (size_t)bn0 * Kdim;

  // staging source coords (inverse of (row&7)<<4 byte swizzle)
  const int srow = (wave << 3) + (lane >> 3);                 // +h*128+r*64
  const int scol = ((lane & 7) ^ (lane >> 3)) << 3;           // f16 elements

  auto stage = [&](int buf, int op, int h, int t) {
    const _Float16* G = op ? Bg : Ag;
    const int kt = t * BK;
#pragma unroll
    for (int r = 0; r < 2; ++r) {
      const _Float16* src = G + (size_t)(h * 128 + r * 64 + srow) * Kdim + kt + scol;
      char* dst = (char*)&lds[buf][op][0] + h * 16384 + r * 8192 + (wave << 10);
      GLD16(src, dst);  // HW adds lane*16 to wave-uniform dst
    }
  };
  auto ldsRd = [&](int buf, int op, int row, int cb) -> half8 {
    int b = row * 128 + cb;
    b ^= (row & 7) << 4;  // 3-bit slot rotation
    return *(const half8*)((const char*)&lds[buf][op][0] + b);
  };

  floatx4 acc[8][4] = {};

  // ---- prologue: tile0 all 4 halves, tile1 B halves; vmcnt(4); barrier ----
  stage(0, 0, 0, 0); stage(0, 0, 1, 0);
  stage(0, 1, 0, 0); stage(0, 1, 1, 0);
  stage(1, 1, 0, 1); stage(1, 1, 1, 1);
  asm volatile("s_waitcnt vmcnt(4)" ::: "memory");
  __builtin_amdgcn_s_barrier();

  for (int t = 0; t < NT; ++t) {
    const int cur = t & 1;
    const bool doA = (t + 1 < NT);
    const bool doB = (t + 2 < NT);
    half8 af[8], bf[2][4];
    const int cb0 = (lane >> 4) * 16;  // k-slice byte base per lane

    // ================ P1: quad (mh0, np0), 12 ds_reads ================
#pragma unroll
    for (int m2 = 0; m2 < 4; ++m2)
#pragma unroll
      for (int ks = 0; ks < 2; ++ks)
        af[m2 * 2 + ks] = ldsRd(cur, 0, wr * 128 + m2 * 16 + (lane & 15), ks * 64 + cb0);
#pragma unroll
    for (int n2 = 0; n2 < 2; ++n2)
#pragma unroll
      for (int ks = 0; ks < 2; ++ks)
        bf[0][n2 * 2 + ks] = ldsRd(cur, 1, wcn * 64 + n2 * 16 + (lane & 15), ks * 64 + cb0);
    if (doA) stage(cur ^ 1, 0, 0, t + 1);
    asm volatile("s_waitcnt lgkmcnt(8)" ::: "memory");
    __builtin_amdgcn_s_barrier();
    asm volatile("s_waitcnt lgkmcnt(0)" ::: "memory");
    __builtin_amdgcn_s_setprio(1);
#pragma unroll
    for (int m2 = 0; m2 < 4; ++m2)
#pragma unroll
      for (int n2 = 0; n2 < 2; ++n2)
#pragma unroll
        for (int ks = 0; ks < 2; ++ks)
          acc[m2][n2] = __builtin_amdgcn_mfma_f32_16x16x32_f16(
              af[m2 * 2 + ks], bf[0][n2 * 2 + ks], acc[m2][n2], 0, 0, 0);
    __builtin_amdgcn_s_setprio(0);
    __builtin_amdgcn_s_barrier();

    // ================ P2: quad (mh0, np1), 4 ds_reads ================
#pragma unroll
    for (int n2 = 0; n2 < 2; ++n2)
#pragma unroll
      for (int ks = 0; ks < 2; ++ks)
        bf[1][n2 * 2 + ks] =
            ldsRd(cur, 1, wcn * 64 + 32 + n2 * 16 + (lane & 15), ks * 64 + cb0);
    if (doA) stage(cur ^ 1, 0, 1, t + 1);
    __builtin_amdgcn_s_barrier();
    asm volatile("s_waitcnt lgkmcnt(0)" ::: "memory");
    __builtin_amdgcn_s_setprio(1);
#pragma unroll
    for (int m2 = 0; m2 < 4; ++m2)
#pragma unroll
      for (int n2 = 0; n2 < 2; ++n2)
#pragma unroll
        for (int ks = 0; ks < 2; ++ks)
          acc[m2][2 + n2] = __builtin_amdgcn_mfma_f32_16x16x32_f16(
              af[m2 * 2 + ks], bf[1][n2 * 2 + ks], acc[m2][2 + n2], 0, 0, 0);
    __builtin_amdgcn_s_setprio(0);
    __builtin_amdgcn_s_barrier();

    // ================ P3: quad (mh1, np0), 8 ds_reads ================
#pragma unroll
    for (int m2 = 0; m2 < 4; ++m2)
#pragma unroll
      for (int ks = 0; ks < 2; ++ks)
        af[m2 * 2 + ks] =
            ldsRd(cur, 0, wr * 128 + 64 + m2 * 16 + (lane & 15), ks * 64 + cb0);
    if (doB) stage(cur, 1, 0, t + 2);
    __builtin_amdgcn_s_barrier();
    asm volatile("s_waitcnt lgkmcnt(0)" ::: "memory");
    __builtin_amdgcn_s_setprio(1);
#pragma unroll
    for (int m2 = 0; m2 < 4; ++m2)
#pragma unroll
      for (int n2 = 0; n2 < 2; ++n2)
#pragma unroll
        for (int ks = 0; ks < 2; ++ks)
          acc[4 + m2][n2] = __builtin_amdgcn_mfma_f32_16x16x32_f16(
              af[m2 * 2 + ks], bf[0][n2 * 2 + ks], acc[4 + m2][n2], 0, 0, 0);
    __builtin_amdgcn_s_setprio(0);
    __builtin_amdgcn_s_barrier();

    // ================ P4: quad (mh1, np1), 0 ds_reads ================
    if (doB) stage(cur, 1, 1, t + 2);
    __builtin_amdgcn_s_barrier();
    __builtin_amdgcn_s_setprio(1);
#pragma unroll
    for (int m2 = 0; m2 < 4; ++m2)
#pragma unroll
      for (int n2 = 0; n2 < 2; ++n2)
#pragma unroll
        for (int ks = 0; ks < 2; ++ks)
          acc[4 + m2][2 + n2] = __builtin_amdgcn_mfma_f32_16x16x32_f16(
              af[m2 * 2 + ks], bf[1][n2 * 2 + ks], acc[4 + m2][2 + n2], 0, 0, 0);
    __builtin_amdgcn_s_setprio(0);
    if (doB) {
      asm volatile("s_waitcnt vmcnt(4)" ::: "memory");  // t+1 resident; B(t+2) in flight
    } else if (doA) {
      asm volatile("s_waitcnt vmcnt(0)" ::: "memory");  // tail: drain A(t+1)
    }
    __builtin_amdgcn_s_barrier();
  }

  // ---- epilogue: fp16round(acc * scale[n]) stored as fp32 ----
  float sc[4];
#pragma unroll
  for (int ni = 0; ni < 4; ++ni)
    sc[ni] = scale[bn0 + wcn * 64 + ni * 16 + (lane & 15)];
#pragma unroll
  for (int mi = 0; mi < 8; ++mi) {
    const int row0 = bm0 + wr * 128 + mi * 16 + (lane >> 4) * 4;
#pragma unroll
    for (int ni = 0; ni < 4; ++ni) {
      const int col = bn0 + wcn * 64 + ni * 16 + (lane & 15);
#pragma unroll
      for (int i = 0; i < 4; ++i)
        Y[(size_t)(row0 + i) * Ndim + col] = (float)(_Float16)(acc[mi][ni][i] * sc[ni]);
    }
  }
}

// ---------------- fallback (ws too small): fused-convert 128^2 ----------------
__global__ __launch_bounds__(256) void gemm_fused(
    const float* __restrict__ Xf, const int* __restrict__ W32,
    const float* __restrict__ scale, float* __restrict__ Y) {
  constexpr int bM = 128, bN = 128, bK = 64;
  __shared__ _Float16 As[bM * bK];
  __shared__ _Float16 Bs[bN * bK];
  const int tid = threadIdx.x, lane = tid & 63, wave = tid >> 6;
  const int wr2 = wave >> 1, wc2 = wave & 1;
  const int bn0 = (int)(blockIdx.x % (Ndim / bN)) * bN;
  const int bm0 = (int)(blockIdx.x / (Ndim / bN)) * bM;
  floatx4 acc[4][4] = {};
  for (int t = 0; t < Kdim / bK; ++t) {
    const int kt = t * bK;
    {
      const int e0 = tid << 5, row = e0 >> 6, col = e0 & 63;
      const float* gp = Xf + (size_t)(bm0 + row) * Kdim + kt + col;
      half8* lp = (half8*)&As[row * bK + col];
#pragma unroll
      for (int v = 0; v < 4; ++v)
        lp[v] = cvt_f8(((const float4*)gp)[2 * v], ((const float4*)gp)[2 * v + 1]);
      const int* gq = W32 + (size_t)(bn0 + row) * Kdim + kt + col;
      half8* lq = (half8*)&Bs[row * bK + col];
#pragma unroll
      for (int v = 0; v < 4; ++v)
        lq[v] = cvt_i8(((const int4*)gq)[2 * v], ((const int4*)gq)[2 * v + 1]);
    }
    __syncthreads();
#pragma unroll
    for (int ks = 0; ks < 2; ++ks) {
      half8 a4[4], b4[4];
#pragma unroll
      for (int i = 0; i < 4; ++i)
        a4[i] = *(const half8*)&As[(wr2 * 64 + i * 16 + (lane & 15)) * bK + ks * 32 + (lane >> 4) * 8];
#pragma unroll
      for (int i = 0; i < 4; ++i)
        b4[i] = *(const half8*)&Bs[(wc2 * 64 + i * 16 + (lane & 15)) * bK + ks * 32 + (lane >> 4) * 8];
#pragma unroll
      for (int m = 0; m < 4; ++m)
#pragma unroll
        for (int n = 0; n < 4; ++n)
          acc[m][n] = __builtin_amdgcn_mfma_f32_16x16x32_f16(a4[m], b4[n], acc[m][n], 0, 0, 0);
    }
    __syncthreads();
  }
  float sc[4];
#pragma unroll
  for (int n = 0; n < 4; ++n) sc[n] = scale[bn0 + wc2 * 64 + n * 16 + (lane & 15)];
#pragma unroll
  for (int m = 0; m < 4; ++m) {
    const int row0 = bm0 + wr2 * 64 + m * 16 + (lane >> 4) * 4;
#pragma unroll
    for (int n = 0; n < 4; ++n) {
      const int col = bn0 + wc2 * 64 + n * 16 + (lane & 15);
#pragma unroll
      for (int i = 0; i < 4; ++i)
        Y[(size_t)(row0 + i) * Ndim + col] = (float)(_Float16)(acc[m][n][i] * sc[n]);
    }
  }
}

extern "C" void kernel_launch(void* const* d_in, const int* in_sizes, int n_in,
                              void* d_out, int out_size, void* d_ws, size_t ws_size,
                              hipStream_t stream) {
  const float* X = (const float*)d_in[0];
  const int* W32 = (const int*)d_in[1];
  const float* scale = (const float*)d_in[2];
  float* Y = (float*)d_out;

  const size_t wbytes = (size_t)Ndim * Kdim * sizeof(_Float16);  // 86 MiB
  const size_t xbytes = (size_t)Mdim * Kdim * sizeof(_Float16);  // 64 MiB

  if (ws_size >= wbytes + xbytes) {
    _Float16* Wh = (_Float16*)d_ws;
    _Float16* Xh = (_Float16*)((char*)d_ws + wbytes);
    conv_both<<<CONVB_TOT, 256, 0, stream>>>(W32, X, Wh, Xh);
    gemm8<<<NWG, 512, 0, stream>>>(Xh, Wh, scale, Y);
  } else {
    gemm_fused<<<(Ndim / 128) * (Mdim / 128), 256, 0, stream>>>(X, W32, scale, Y);
  }
}